// Round 1
// baseline (666.531 us; speedup 1.0000x reference)
//
#include <hip/hip_runtime.h>
#include <stdint.h>

#define S_LEN 2048
#define DMODEL 2048
#define NH 16
#define NKV 4
#define HD 128

typedef __attribute__((ext_vector_type(8))) short bf16x8_t;
typedef __attribute__((ext_vector_type(4))) short bf16x4_t;
typedef __attribute__((ext_vector_type(4))) float f32x4;

static __device__ __forceinline__ short f2bf(float f) {
  uint32_t x = __float_as_uint(f);
  uint32_t r = (x + 0x7FFFu + ((x >> 16) & 1u)) >> 16;
  return (short)r;
}

// ---------------- f32 -> bf16 elementwise (8/thread) ----------------
__global__ void cvt_bf16(const float* __restrict__ in, short* __restrict__ out, int n8) {
  int idx = blockIdx.x * 256 + threadIdx.x;
  if (idx >= n8) return;
  const float4* p = (const float4*)in + 2 * (size_t)idx;
  float4 a = p[0], b = p[1];
  bf16x8_t o;
  o[0] = f2bf(a.x); o[1] = f2bf(a.y); o[2] = f2bf(a.z); o[3] = f2bf(a.w);
  o[4] = f2bf(b.x); o[5] = f2bf(b.y); o[6] = f2bf(b.z); o[7] = f2bf(b.w);
  ((bf16x8_t*)out)[idx] = o;
}

// ---------------- transpose f32 -> bf16: out[c][r] = in[r][c] ----------------
__global__ void transpose_f32_bf16(const float* __restrict__ in, short* __restrict__ out,
                                   int inStride, int outStride,
                                   long zInOff, long zOutOff) {
  __shared__ float tile[32][33];
  in  += (size_t)blockIdx.z * zInOff;
  out += (size_t)blockIdx.z * zOutOff;
  int c0 = blockIdx.x * 32, r0 = blockIdx.y * 32;
  int tx = threadIdx.x, ty = threadIdx.y;
  for (int i = ty; i < 32; i += 8)
    tile[i][tx] = in[(size_t)(r0 + i) * inStride + c0 + tx];
  __syncthreads();
  for (int i = ty; i < 32; i += 8)
    out[(size_t)(c0 + i) * outStride + r0 + tx] = f2bf(tile[tx][i]);
}

// ---------------- RoPE: xf[s][h*HD+d] (f32) -> out[h][s][d] (bf16) ----------------
__global__ void rope_heads(const float* __restrict__ xf, const float* __restrict__ fc,
                           const float* __restrict__ fs, short* __restrict__ outp,
                           int rowStride) {
  int s = blockIdx.x;
  int i = threadIdx.x;                              // 0..63 freq index
  int h = blockIdx.y * blockDim.y + threadIdx.y;
  float c = fc[s * 64 + i], sn = fs[s * 64 + i];
  const float* xr = xf + (size_t)s * rowStride + h * HD;
  float t0 = xr[2 * i], t1 = xr[2 * i + 1];
  float o0 = t0 * c - t1 * sn;
  float o1 = t0 * sn + t1 * c;
  short* orow = outp + ((size_t)h * S_LEN + s) * HD;
  uint32_t pk = (uint32_t)(uint16_t)f2bf(o0) | ((uint32_t)(uint16_t)f2bf(o1) << 16);
  *(uint32_t*)&orow[2 * i] = pk;
}

// ---------------- bf16 GEMM: C[M][N] (f32) = A[M][K] * Bt[N][K]^T ----------------
// 128x128 tile, BK=32, 256 threads (4 waves, 2x2), 4x4 16x16 frags per wave.
__global__ __launch_bounds__(256) void gemm_bt(const short* __restrict__ A,
                                               const short* __restrict__ Bt,
                                               float* __restrict__ C,
                                               int M, int N, int K) {
  __shared__ uint4 lds[1024];                 // A tile 8KB [0,512), B tile 8KB [512,1024)
  const int tid = threadIdx.x;
  const int wid = tid >> 6, lane = tid & 63;
  const int lq = lane & 15, g = lane >> 4;
  const int bm = blockIdx.y * 128, bn = blockIdx.x * 128;
  const int wr = wid >> 1, wc = wid & 1;

  f32x4 acc[4][4] = {};

  const int c0 = tid;                          // chunks c0 and c0+256
  const short* Ag0 = A + (size_t)(bm + (c0 >> 2)) * K + (c0 & 3) * 8;
  const short* Ag1 = A + (size_t)(bm + ((c0 + 256) >> 2)) * K + ((c0 + 256) & 3) * 8;
  const short* Bg0 = Bt + (size_t)(bn + (c0 >> 2)) * K + (c0 & 3) * 8;
  const short* Bg1 = Bt + (size_t)(bn + ((c0 + 256) >> 2)) * K + ((c0 + 256) & 3) * 8;
  const char* ldsc = (const char*)lds;

  for (int k0 = 0; k0 < K; k0 += 32) {
    uint4 a0 = *(const uint4*)(Ag0 + k0);
    uint4 a1 = *(const uint4*)(Ag1 + k0);
    uint4 b0 = *(const uint4*)(Bg0 + k0);
    uint4 b1 = *(const uint4*)(Bg1 + k0);
    __syncthreads();
    lds[c0] = a0; lds[c0 + 256] = a1;
    lds[512 + c0] = b0; lds[512 + c0 + 256] = b1;
    __syncthreads();
    bf16x8_t af[4], bfr[4];
#pragma unroll
    for (int mi = 0; mi < 4; mi++)
      af[mi] = *(const bf16x8_t*)(ldsc + (wr * 64 + mi * 16 + lq) * 64 + g * 16);
#pragma unroll
    for (int ni = 0; ni < 4; ni++)
      bfr[ni] = *(const bf16x8_t*)(ldsc + 8192 + (wc * 64 + ni * 16 + lq) * 64 + g * 16);
#pragma unroll
    for (int mi = 0; mi < 4; mi++)
#pragma unroll
      for (int ni = 0; ni < 4; ni++)
        acc[mi][ni] = __builtin_amdgcn_mfma_f32_16x16x32_bf16(af[mi], bfr[ni], acc[mi][ni], 0, 0, 0);
  }
#pragma unroll
  for (int mi = 0; mi < 4; mi++) {
#pragma unroll
    for (int r = 0; r < 4; r++) {
      int row = bm + wr * 64 + mi * 16 + g * 4 + r;
      float* Crow = C + (size_t)row * N + bn + wc * 64;
#pragma unroll
      for (int ni = 0; ni < 4; ni++)
        Crow[ni * 16 + lq] = acc[mi][ni][r];
    }
  }
}

// ---------------- flash attention ----------------
// Q [NH][S][HD] bf16, K [NKV][S][HD] bf16, Vt [NKV][HD][S] bf16 -> Oatt [S][NH*HD] bf16
// 4 independent waves/block; wave = 16 q rows; KV tile = 32.
// Swapped QK^T: lane holds 8 scores of q-row (lane&15) at kv slots {4g+r, 16+4g+r}.
__global__ __launch_bounds__(256) void flash_attn(const short* __restrict__ Q,
                                                  const short* __restrict__ Kb,
                                                  const short* __restrict__ Vt,
                                                  short* __restrict__ Oatt) {
  const int h = blockIdx.y, kvh = h >> 2;
  const int wid = threadIdx.x >> 6, lane = threadIdx.x & 63;
  const int lq = lane & 15, g = lane >> 4;
  const int q0 = blockIdx.x * 64 + wid * 16;
  const float scale = 0.0883883476483184f;   // 1/sqrt(128)

  const short* Qb = Q + ((size_t)h * S_LEN + q0) * HD;
  bf16x8_t qf[4];
#pragma unroll
  for (int kk = 0; kk < 4; kk++)
    qf[kk] = *(const bf16x8_t*)(Qb + lq * HD + kk * 32 + g * 8);

  f32x4 oa[8] = {};
  float m_run = -1e30f, l_run = 0.f;

  const short* Kh = Kb + (size_t)kvh * S_LEN * HD;
  const short* Vh = Vt + (size_t)kvh * HD * S_LEN;

  const int ntiles = (q0 + 15) / 32 + 1;
  for (int t = 0; t < ntiles; t++) {
    const int kv0 = t * 32;
    // --- swapped QK^T: T[kv][q] ---
    f32x4 sc0 = {}, sc1 = {};
    const short* Kt0 = Kh + (size_t)(kv0 + lq) * HD;
    const short* Kt1 = Kh + (size_t)(kv0 + 16 + lq) * HD;
#pragma unroll
    for (int kk = 0; kk < 4; kk++) {
      bf16x8_t a0 = *(const bf16x8_t*)(Kt0 + kk * 32 + g * 8);
      sc0 = __builtin_amdgcn_mfma_f32_16x16x32_bf16(a0, qf[kk], sc0, 0, 0, 0);
    }
#pragma unroll
    for (int kk = 0; kk < 4; kk++) {
      bf16x8_t a1 = *(const bf16x8_t*)(Kt1 + kk * 32 + g * 8);
      sc1 = __builtin_amdgcn_mfma_f32_16x16x32_bf16(a1, qf[kk], sc1, 0, 0, 0);
    }
    // --- online softmax (per q-row = lane&15; row is split across the 4 g-lanes) ---
    const int q_abs = q0 + lq;
    float s8[8];
#pragma unroll
    for (int r = 0; r < 4; r++) {
      int kva = kv0 + 4 * g + r;
      s8[r]     = (kva <= q_abs)      ? sc0[r] * scale : -1e30f;
      s8[4 + r] = (kva + 16 <= q_abs) ? sc1[r] * scale : -1e30f;
    }
    float mx = s8[0];
#pragma unroll
    for (int j = 1; j < 8; j++) mx = fmaxf(mx, s8[j]);
    mx = fmaxf(mx, __shfl_xor(mx, 16));
    mx = fmaxf(mx, __shfl_xor(mx, 32));
    float m_new = fmaxf(m_run, mx);
    float p8[8], psum = 0.f;
#pragma unroll
    for (int j = 0; j < 8; j++) { p8[j] = __expf(s8[j] - m_new); psum += p8[j]; }
    psum += __shfl_xor(psum, 16);
    psum += __shfl_xor(psum, 32);
    float f = __expf(m_run - m_new);
    l_run = l_run * f + psum;
    m_run = m_new;
    // pack P: a-frag element j <-> kv slot (j<4: kv0+4g+j ; j>=4: kv0+16+4g+(j-4))
    bf16x8_t pf;
#pragma unroll
    for (int j = 0; j < 8; j++) pf[j] = f2bf(p8[j]);
    // rescale O (O rows live at q = 4g+r; fetch f from lane 4g+r)
    float fr[4];
#pragma unroll
    for (int r = 0; r < 4; r++) fr[r] = __shfl(f, 4 * g + r);
#pragma unroll
    for (int nt = 0; nt < 8; nt++)
#pragma unroll
      for (int r = 0; r < 4; r++) oa[nt][r] *= fr[r];
    // --- PV: O += P * V, V fragments from Vt with matching slot order ---
#pragma unroll
    for (int nt = 0; nt < 8; nt++) {
      const short* vp = Vh + (size_t)(nt * 16 + lq) * S_LEN + kv0 + 4 * g;
      bf16x4_t v0 = *(const bf16x4_t*)vp;
      bf16x4_t v1 = *(const bf16x4_t*)(vp + 16);
      bf16x8_t vf;
#pragma unroll
      for (int j = 0; j < 4; j++) { vf[j] = v0[j]; vf[4 + j] = v1[j]; }
      oa[nt] = __builtin_amdgcn_mfma_f32_16x16x32_bf16(pf, vf, oa[nt], 0, 0, 0);
    }
  }
  // finalize: divide by l (per O-row), write bf16
  float lr[4];
#pragma unroll
  for (int r = 0; r < 4; r++) lr[r] = __shfl(l_run, 4 * g + r);
#pragma unroll
  for (int nt = 0; nt < 8; nt++) {
#pragma unroll
    for (int r = 0; r < 4; r++) {
      int row = q0 + 4 * g + r;
      Oatt[(size_t)row * (NH * HD) + h * HD + nt * 16 + lq] = f2bf(oa[nt][r] / lr[r]);
    }
  }
}

// ---------------- launch ----------------
extern "C" void kernel_launch(void* const* d_in, const int* in_sizes, int n_in,
                              void* d_out, int out_size, void* d_ws, size_t ws_size,
                              hipStream_t stream) {
  const float* x  = (const float*)d_in[0];
  const float* wq = (const float*)d_in[1];
  const float* wk = (const float*)d_in[2];
  const float* wv = (const float*)d_in[3];
  const float* wo = (const float*)d_in[4];
  const float* fc = (const float*)d_in[5];
  const float* fs = (const float*)d_in[6];
  // d_in[7] (mask) is exactly causal tril -> applied analytically
  float* out = (float*)d_out;

  char* ws = (char*)d_ws;
  const size_t MB = 1024 * 1024;
  if (ws_size < 72 * MB) return;  // workspace plan needs 72MB
  short* xb  = (short*)(ws);             // 8MB  x bf16 [S][D]
  short* wqT = (short*)(ws + 8 * MB);    // 8MB  [N=2048][K=2048]
  short* wkT = (short*)(ws + 16 * MB);   // 2MB  [512][2048]
  short* wvT = (short*)(ws + 18 * MB);   // 2MB
  short* woT = (short*)(ws + 20 * MB);   // 8MB
  float* xqf = (float*)(ws + 28 * MB);   // 16MB x@wq f32
  float* xkf = (float*)(ws + 44 * MB);   // 4MB
  float* xvf = (float*)(ws + 48 * MB);   // 4MB
  short* qbf = (short*)(ws + 52 * MB);   // 8MB  [NH][S][HD]
  short* kbf = (short*)(ws + 60 * MB);   // 2MB  [NKV][S][HD]
  short* vT  = (short*)(ws + 62 * MB);   // 2MB  [NKV][HD][S]
  short* abf = (short*)(ws + 64 * MB);   // 8MB  attn out bf16 [S][NH*HD]

  dim3 tb(32, 8);
  cvt_bf16<<<2048, 256, 0, stream>>>(x, xb, (S_LEN * DMODEL) / 8);
  transpose_f32_bf16<<<dim3(64, 64, 1), tb, 0, stream>>>(wq, wqT, 2048, 2048, 0, 0);
  transpose_f32_bf16<<<dim3(16, 64, 1), tb, 0, stream>>>(wk, wkT, 512, 2048, 0, 0);
  transpose_f32_bf16<<<dim3(16, 64, 1), tb, 0, stream>>>(wv, wvT, 512, 2048, 0, 0);
  transpose_f32_bf16<<<dim3(64, 64, 1), tb, 0, stream>>>(wo, woT, 2048, 2048, 0, 0);

  gemm_bt<<<dim3(16, 16), 256, 0, stream>>>(xb, wqT, xqf, 2048, 2048, 2048);
  gemm_bt<<<dim3(4, 16),  256, 0, stream>>>(xb, wkT, xkf, 2048, 512, 2048);
  gemm_bt<<<dim3(4, 16),  256, 0, stream>>>(xb, wvT, xvf, 2048, 512, 2048);

  rope_heads<<<dim3(2048, 4), dim3(64, 4), 0, stream>>>(xqf, fc, fs, qbf, 2048);
  rope_heads<<<dim3(2048, 1), dim3(64, 4), 0, stream>>>(xkf, fc, fs, kbf, 512);
  // V^T per kv head: in cols [z*128, z*128+128) of xvf -> vT[z][d][s]
  transpose_f32_bf16<<<dim3(4, 64, 4), tb, 0, stream>>>(xvf, vT, 512, 2048, 128, 128L * 2048);

  flash_attn<<<dim3(32, 16), 256, 0, stream>>>(qbf, kbf, vT, abf);

  gemm_bt<<<dim3(16, 16), 256, 0, stream>>>(abf, woT, out, 2048, 2048, 2048);
}

// Round 3
// 330.456 us; speedup vs baseline: 2.0170x; 2.0170x over previous
//
#include <hip/hip_runtime.h>
#include <stdint.h>

#define S_LEN 2048
#define DMODEL 2048
#define NH 16
#define NKV 4
#define HD 128

typedef __attribute__((ext_vector_type(8))) short bf16x8_t;
typedef __attribute__((ext_vector_type(4))) short bf16x4_t;
typedef __attribute__((ext_vector_type(4))) float f32x4;

static __device__ __forceinline__ short f2bf(float f) {
  uint32_t x = __float_as_uint(f);
  uint32_t r = (x + 0x7FFFu + ((x >> 16) & 1u)) >> 16;
  return (short)r;
}

static __device__ __forceinline__ void gload16(const void* g, void* l) {
  __builtin_amdgcn_global_load_lds((const __attribute__((address_space(1))) void*)g,
                                   (__attribute__((address_space(3))) void*)l, 16, 0, 0);
}

// ---------------- f32 -> bf16 elementwise (8/thread) ----------------
__global__ void cvt_bf16(const float* __restrict__ in, short* __restrict__ out, int n8) {
  int idx = blockIdx.x * 256 + threadIdx.x;
  if (idx >= n8) return;
  const float4* p = (const float4*)in + 2 * (size_t)idx;
  float4 a = p[0], b = p[1];
  bf16x8_t o;
  o[0] = f2bf(a.x); o[1] = f2bf(a.y); o[2] = f2bf(a.z); o[3] = f2bf(a.w);
  o[4] = f2bf(b.x); o[5] = f2bf(b.y); o[6] = f2bf(b.z); o[7] = f2bf(b.w);
  ((bf16x8_t*)out)[idx] = o;
}

// ---------------- transpose f32 -> bf16: out[c][r] = in[r][c] ----------------
__global__ void transpose_f32_bf16(const float* __restrict__ in, short* __restrict__ out,
                                   int inStride, int outStride,
                                   long zInOff, long zOutOff) {
  __shared__ float tile[32][33];
  in  += (size_t)blockIdx.z * zInOff;
  out += (size_t)blockIdx.z * zOutOff;
  int c0 = blockIdx.x * 32, r0 = blockIdx.y * 32;
  int tx = threadIdx.x, ty = threadIdx.y;
  for (int i = ty; i < 32; i += 8)
    tile[i][tx] = in[(size_t)(r0 + i) * inStride + c0 + tx];
  __syncthreads();
  for (int i = ty; i < 32; i += 8)
    out[(size_t)(c0 + i) * outStride + r0 + tx] = f2bf(tile[tx][i]);
}

// ---------------- RoPE: xf[s][h*HD+d] (f32) -> out[h][s][d] (bf16) ----------------
__global__ void rope_heads(const float* __restrict__ xf, const float* __restrict__ fc,
                           const float* __restrict__ fs, short* __restrict__ outp,
                           int rowStride) {
  int s = blockIdx.x;
  int i = threadIdx.x;                              // 0..63 freq index
  int h = blockIdx.y * blockDim.y + threadIdx.y;
  float c = fc[s * 64 + i], sn = fs[s * 64 + i];
  const float* xr = xf + (size_t)s * rowStride + h * HD;
  float t0 = xr[2 * i], t1 = xr[2 * i + 1];
  float o0 = t0 * c - t1 * sn;
  float o1 = t0 * sn + t1 * c;
  short* orow = outp + ((size_t)h * S_LEN + s) * HD;
  uint32_t pk = (uint32_t)(uint16_t)f2bf(o0) | ((uint32_t)(uint16_t)f2bf(o1) << 16);
  *(uint32_t*)&orow[2 * i] = pk;
}

// ---------------- bf16 GEMM: C[M][N] (f32) = A[M][K] * Bt[N][K]^T ----------------
// BM=128, BN=64, BK=32. 128 threads (2 waves stacked in M), acc 4x4 per wave.
// Staging via global_load_lds width-16 (ladder step 3 structure).
__global__ __launch_bounds__(128) void gemm_bt(const short* __restrict__ A,
                                               const short* __restrict__ Bt,
                                               float* __restrict__ C,
                                               int M, int N, int K) {
  __shared__ char smem[12288];            // A tile 8KB [0,8192), B tile 4KB
  const int tid = threadIdx.x;
  const int wid = tid >> 6, lane = tid & 63;
  const int lq = lane & 15, g = lane >> 4;
  const int bm = blockIdx.y * 128, bn = blockIdx.x * 64;

  f32x4 acc[4][4] = {};

  // per-thread staging source pointers (granule = 16B; A tile 512 granules, B 256)
  const short* Asrc[4];
  const short* Bsrc[2];
#pragma unroll
  for (int u = 0; u < 4; u++) {
    int p = wid * 64 + u * 128 + lane;
    Asrc[u] = A + (size_t)(bm + (p >> 2)) * K + (p & 3) * 8;
  }
#pragma unroll
  for (int u = 0; u < 2; u++) {
    int p = wid * 64 + u * 128 + lane;
    Bsrc[u] = Bt + (size_t)(bn + (p >> 2)) * K + (p & 3) * 8;
  }
  char* la = smem;
  char* lb = smem + 8192;

  for (int k0 = 0; k0 < K; k0 += 32) {
    __syncthreads();
#pragma unroll
    for (int u = 0; u < 4; u++)
      gload16(Asrc[u] + k0, la + wid * 1024 + u * 2048);
#pragma unroll
    for (int u = 0; u < 2; u++)
      gload16(Bsrc[u] + k0, lb + wid * 1024 + u * 2048);
    __syncthreads();
    bf16x8_t af[4], bfr[4];
#pragma unroll
    for (int mi = 0; mi < 4; mi++)
      af[mi] = *(const bf16x8_t*)(la + (wid * 64 + mi * 16 + lq) * 64 + g * 16);
#pragma unroll
    for (int ni = 0; ni < 4; ni++)
      bfr[ni] = *(const bf16x8_t*)(lb + (ni * 16 + lq) * 64 + g * 16);
#pragma unroll
    for (int mi = 0; mi < 4; mi++)
#pragma unroll
      for (int ni = 0; ni < 4; ni++)
        acc[mi][ni] = __builtin_amdgcn_mfma_f32_16x16x32_bf16(af[mi], bfr[ni], acc[mi][ni], 0, 0, 0);
  }
#pragma unroll
  for (int mi = 0; mi < 4; mi++) {
#pragma unroll
    for (int r = 0; r < 4; r++) {
      int row = bm + wid * 64 + mi * 16 + g * 4 + r;
      float* Crow = C + (size_t)row * N + bn;
#pragma unroll
      for (int ni = 0; ni < 4; ni++)
        Crow[ni * 16 + lq] = acc[mi][ni][r];
    }
  }
}

// ---------------- flash attention ----------------
// Q [NH][S][HD] bf16, K [NKV][S][HD] bf16, Vt [NKV][HD][S] bf16 -> Oatt [S][NH*HD] bf16
// 128-thread blocks (2 waves x 16 q-rows = 32-row q-tile). KVBLK=64.
// K/V double-buffered in LDS via global_load_lds; XOR swizzle (granule ^ (row&7))
// applied on BOTH stage-source and read (rule #21). Work-balanced: block does
// q-tiles (qi, 63-qi) -> exactly 33 KV tiles per block.
__global__ __launch_bounds__(128) void flash_attn(const short* __restrict__ Q,
                                                  const short* __restrict__ Kb,
                                                  const short* __restrict__ Vt,
                                                  short* __restrict__ Oatt) {
  __shared__ char smem[65536];   // buf b: K at b*32768 (16KB), V at b*32768+16384 (16KB)
  const int h = blockIdx.y, kvh = h >> 2;
  const int pair = blockIdx.x;           // 0..31
  const int wid = threadIdx.x >> 6, lane = threadIdx.x & 63;
  const int lq = lane & 15, g = lane >> 4;
  const float scale2 = 0.0883883476483184f * 1.4426950408889634f; // 1/sqrt(HD)*log2(e)
  const short* Kh = Kb + (size_t)kvh * S_LEN * HD;
  const short* Vh = Vt + (size_t)kvh * HD * S_LEN;

  // staging source offsets (lane-dependent, tile-relative), swizzled granule
  int kOff[8], vOff[8];
#pragma unroll
  for (int u = 0; u < 8; u++) {
    int p = wid * 64 + u * 128 + lane;
    int kr = p >> 4, kc = (p & 15) ^ (kr & 7);
    kOff[u] = kr * HD + kc * 8;          // shorts
    int vd = p >> 3, vc = (p & 7) ^ (vd & 7);
    vOff[u] = vd * S_LEN + vc * 8;       // shorts
  }
  const int swz = lq & 7;                // (row & 7) for all fragment reads

  for (int pass = 0; pass < 2; pass++) {
    const int qi = pass ? (63 - pair) : pair;     // 32-row q tile index
    const int q0 = qi * 32 + wid * 16;            // this wave's 16 rows
    const int ntiles = (qi >> 1) + 1;
    const int q_abs = q0 + lq;

    const short* Qb = Q + ((size_t)h * S_LEN + q0) * HD;
    bf16x8_t qf[4];
#pragma unroll
    for (int kk = 0; kk < 4; kk++)
      qf[kk] = *(const bf16x8_t*)(Qb + lq * HD + kk * 32 + g * 8);

    f32x4 oa[8] = {};
    float m_run = -1e30f, l_run = 0.f;

    // prologue: stage tile 0 -> buf 0
#pragma unroll
    for (int u = 0; u < 8; u++) {
      gload16(Kh + kOff[u], smem + wid * 1024 + u * 2048);
      gload16(Vh + vOff[u], smem + 16384 + wid * 1024 + u * 2048);
    }
    __syncthreads();

    for (int t = 0; t < ntiles; t++) {
      const int cur = t & 1;
      const int kv0 = t * 64;
      if (t + 1 < ntiles) {               // stage next tile into other buffer
        const short* Ks = Kh + (size_t)(kv0 + 64) * HD;
        const short* Vs = Vh + kv0 + 64;
        char* dk = smem + (cur ^ 1) * 32768;
        char* dv = dk + 16384;
#pragma unroll
        for (int u = 0; u < 8; u++) {
          gload16(Ks + kOff[u], dk + wid * 1024 + u * 2048);
          gload16(Vs + vOff[u], dv + wid * 1024 + u * 2048);
        }
      }
      const char* lk = smem + cur * 32768;
      const char* lv = lk + 16384;

      // --- swapped QK^T: sc[sub][r] = score(q=q0+lq, kv=kv0+sub*16+4g+r) ---
      f32x4 sc[4] = {};
#pragma unroll
      for (int sub = 0; sub < 4; sub++) {
        const char* krow = lk + (sub * 16 + lq) * 256;
#pragma unroll
        for (int kk = 0; kk < 4; kk++) {
          bf16x8_t kf = *(const bf16x8_t*)(krow + (((kk * 4 + g) ^ swz) << 4));
          sc[sub] = __builtin_amdgcn_mfma_f32_16x16x32_bf16(kf, qf[kk], sc[sub], 0, 0, 0);
        }
      }
      // --- online softmax (exp2 domain), mask only on diagonal tile ---
      float s16[16];
      if (t == ntiles - 1) {
#pragma unroll
        for (int sub = 0; sub < 4; sub++)
#pragma unroll
          for (int r = 0; r < 4; r++) {
            int kva = kv0 + sub * 16 + 4 * g + r;
            s16[sub * 4 + r] = (kva <= q_abs) ? sc[sub][r] * scale2 : -1e30f;
          }
      } else {
#pragma unroll
        for (int sub = 0; sub < 4; sub++)
#pragma unroll
          for (int r = 0; r < 4; r++)
            s16[sub * 4 + r] = sc[sub][r] * scale2;
      }
      float mx = s16[0];
#pragma unroll
      for (int j = 1; j < 16; j++) mx = fmaxf(mx, s16[j]);
      mx = fmaxf(mx, __shfl_xor(mx, 16));
      mx = fmaxf(mx, __shfl_xor(mx, 32));
      float m_new = fmaxf(m_run, mx);
      float p16[16], psum = 0.f;
#pragma unroll
      for (int j = 0; j < 16; j++) { p16[j] = exp2f(s16[j] - m_new); psum += p16[j]; }
      psum += __shfl_xor(psum, 16);
      psum += __shfl_xor(psum, 32);
      float f = exp2f(m_run - m_new);
      l_run = l_run * f + psum;
      m_run = m_new;

      bf16x8_t pf0, pf1;
#pragma unroll
      for (int j = 0; j < 8; j++) { pf0[j] = f2bf(p16[j]); pf1[j] = f2bf(p16[8 + j]); }
      float fr[4];
#pragma unroll
      for (int r = 0; r < 4; r++) fr[r] = __shfl(f, 4 * g + r);
#pragma unroll
      for (int nt = 0; nt < 8; nt++)
#pragma unroll
        for (int r = 0; r < 4; r++) oa[nt][r] *= fr[r];

      // --- PV: O += P * V ---
      const int gh = g >> 1;
#pragma unroll
      for (int nt = 0; nt < 8; nt++) {
        const char* vrow = lv + (nt * 16 + lq) * 128 + (g & 1) * 8;
#pragma unroll
        for (int ks = 0; ks < 2; ks++) {
          bf16x4_t v0 = *(const bf16x4_t*)(vrow + (((ks * 4 + gh) ^ swz) << 4));
          bf16x4_t v1 = *(const bf16x4_t*)(vrow + (((ks * 4 + 2 + gh) ^ swz) << 4));
          bf16x8_t vf;
#pragma unroll
          for (int j = 0; j < 4; j++) { vf[j] = v0[j]; vf[4 + j] = v1[j]; }
          oa[nt] = __builtin_amdgcn_mfma_f32_16x16x32_bf16(ks ? pf1 : pf0, vf, oa[nt], 0, 0, 0);
        }
      }
      __syncthreads();
    }

    // --- finalize: O /= l, write bf16 ---
    float lr[4];
#pragma unroll
    for (int r = 0; r < 4; r++) lr[r] = 1.0f / __shfl(l_run, 4 * g + r);
#pragma unroll
    for (int nt = 0; nt < 8; nt++)
#pragma unroll
      for (int r = 0; r < 4; r++) {
        int row = q0 + 4 * g + r;
        Oatt[(size_t)row * (NH * HD) + h * HD + nt * 16 + lq] = f2bf(oa[nt][r] * lr[r]);
      }
  }
}

// ---------------- launch ----------------
extern "C" void kernel_launch(void* const* d_in, const int* in_sizes, int n_in,
                              void* d_out, int out_size, void* d_ws, size_t ws_size,
                              hipStream_t stream) {
  const float* x  = (const float*)d_in[0];
  const float* wq = (const float*)d_in[1];
  const float* wk = (const float*)d_in[2];
  const float* wv = (const float*)d_in[3];
  const float* wo = (const float*)d_in[4];
  const float* fc = (const float*)d_in[5];
  const float* fs = (const float*)d_in[6];
  // d_in[7] (mask) is exactly causal tril -> applied analytically
  float* out = (float*)d_out;

  char* ws = (char*)d_ws;
  const size_t MB = 1024 * 1024;
  if (ws_size < 72 * MB) return;
  short* xb    = (short*)(ws);            // 8MB  x bf16 [S][D]
  short* wqkvT = (short*)(ws + 8 * MB);   // 12MB [3072][2048] (wq^T | wk^T | wv^T)
  short* woT   = (short*)(ws + 20 * MB);  // 8MB  [2048][2048]
  float* xqkvf = (float*)(ws + 28 * MB);  // 24MB x@wqkv f32 [2048][3072]
  short* qbf   = (short*)(ws + 52 * MB);  // 8MB  [NH][S][HD]
  short* kbf   = (short*)(ws + 60 * MB);  // 2MB  [NKV][S][HD]
  short* vT    = (short*)(ws + 62 * MB);  // 2MB  [NKV][HD][S]
  short* abf   = (short*)(ws + 64 * MB);  // 8MB  attn out bf16 [S][NH*HD]

  dim3 tb(32, 8);
  cvt_bf16<<<2048, 256, 0, stream>>>(x, xb, (S_LEN * DMODEL) / 8);
  transpose_f32_bf16<<<dim3(64, 64, 1), tb, 0, stream>>>(wq, wqkvT, 2048, 2048, 0, 0);
  transpose_f32_bf16<<<dim3(16, 64, 1), tb, 0, stream>>>(wk, wqkvT + (size_t)2048 * 2048, 512, 2048, 0, 0);
  transpose_f32_bf16<<<dim3(16, 64, 1), tb, 0, stream>>>(wv, wqkvT + (size_t)2560 * 2048, 512, 2048, 0, 0);
  transpose_f32_bf16<<<dim3(64, 64, 1), tb, 0, stream>>>(wo, woT, 2048, 2048, 0, 0);

  // fused QKV projection: [2048][2048] x [2048][3072] -> xqkvf [2048][3072]
  gemm_bt<<<dim3(48, 16), 128, 0, stream>>>(xb, wqkvT, xqkvf, 2048, 3072, 2048);

  rope_heads<<<dim3(2048, 4), dim3(64, 4), 0, stream>>>(xqkvf, fc, fs, qbf, 3072);
  rope_heads<<<dim3(2048, 1), dim3(64, 4), 0, stream>>>(xqkvf + 2048, fc, fs, kbf, 3072);
  // V^T per kv head: cols [2560 + z*128, ...+128) of xqkvf -> vT[z][d][s]
  transpose_f32_bf16<<<dim3(4, 64, 4), tb, 0, stream>>>(xqkvf + 2560, vT, 3072, 2048, 128, 128L * 2048);

  flash_attn<<<dim3(32, 16), 128, 0, stream>>>(qbf, kbf, vT, abf);

  // output projection
  gemm_bt<<<dim3(32, 16), 128, 0, stream>>>(abf, woT, out, 2048, 2048, 2048);
}

// Round 9
// 323.363 us; speedup vs baseline: 2.0612x; 1.0219x over previous
//
#include <hip/hip_runtime.h>
#include <stdint.h>

#define S_LEN 2048
#define DMODEL 2048
#define NH 16
#define NKV 4
#define HD 128

typedef __attribute__((ext_vector_type(8))) short bf16x8_t;
typedef __attribute__((ext_vector_type(4))) short bf16x4_t;
typedef __attribute__((ext_vector_type(4))) float f32x4;

static __device__ __forceinline__ short f2bf(float f) {
  uint32_t x = __float_as_uint(f);
  uint32_t r = (x + 0x7FFFu + ((x >> 16) & 1u)) >> 16;
  return (short)r;
}

static __device__ __forceinline__ void gload16(const void* g, void* l) {
  __builtin_amdgcn_global_load_lds((const __attribute__((address_space(1))) void*)g,
                                   (__attribute__((address_space(3))) void*)l, 16, 0, 0);
}

// ---------------- f32 -> bf16 elementwise (8/thread) ----------------
__global__ void cvt_bf16(const float* __restrict__ in, short* __restrict__ out, int n8) {
  int idx = blockIdx.x * 256 + threadIdx.x;
  if (idx >= n8) return;
  const float4* p = (const float4*)in + 2 * (size_t)idx;
  float4 a = p[0], b = p[1];
  bf16x8_t o;
  o[0] = f2bf(a.x); o[1] = f2bf(a.y); o[2] = f2bf(a.z); o[3] = f2bf(a.w);
  o[4] = f2bf(b.x); o[5] = f2bf(b.y); o[6] = f2bf(b.z); o[7] = f2bf(b.w);
  ((bf16x8_t*)out)[idx] = o;
}

// ---------------- transpose f32 -> bf16: out[c][r] = in[r][c] ----------------
__global__ void transpose_f32_bf16(const float* __restrict__ in, short* __restrict__ out,
                                   int inStride, int outStride,
                                   long zInOff, long zOutOff) {
  __shared__ float tile[32][33];
  in  += (size_t)blockIdx.z * zInOff;
  out += (size_t)blockIdx.z * zOutOff;
  int c0 = blockIdx.x * 32, r0 = blockIdx.y * 32;
  int tx = threadIdx.x, ty = threadIdx.y;
  for (int i = ty; i < 32; i += 8)
    tile[i][tx] = in[(size_t)(r0 + i) * inStride + c0 + tx];
  __syncthreads();
  for (int i = ty; i < 32; i += 8)
    out[(size_t)(c0 + i) * outStride + r0 + tx] = f2bf(tile[tx][i]);
}

// ---------------- transpose bf16 -> bf16: out[c][r] = in[r][c] ----------------
__global__ void transpose_bf16(const short* __restrict__ in, short* __restrict__ out,
                               int inStride, int outStride,
                               long zInOff, long zOutOff) {
  __shared__ short tile[32][33];
  in  += (size_t)blockIdx.z * zInOff;
  out += (size_t)blockIdx.z * zOutOff;
  int c0 = blockIdx.x * 32, r0 = blockIdx.y * 32;
  int tx = threadIdx.x, ty = threadIdx.y;
  for (int i = ty; i < 32; i += 8)
    tile[i][tx] = in[(size_t)(r0 + i) * inStride + c0 + tx];
  __syncthreads();
  for (int i = ty; i < 32; i += 8)
    out[(size_t)(c0 + i) * outStride + r0 + tx] = tile[tx][i];
}

// ---------------- RoPE (bf16 in): xf[s][h*HD+d] -> out[h][s][d] (bf16, *oscale) ----
__global__ void rope_heads(const short* __restrict__ xf, const float* __restrict__ fc,
                           const float* __restrict__ fs, short* __restrict__ outp,
                           int rowStride, float oscale) {
  int s = blockIdx.x;
  int i = threadIdx.x;                              // 0..63 freq index
  int h = blockIdx.y * blockDim.y + threadIdx.y;
  float c = fc[s * 64 + i], sn = fs[s * 64 + i];
  const short* xr = xf + (size_t)s * rowStride + h * HD;
  uint32_t w = *(const uint32_t*)&xr[2 * i];
  float t0 = __uint_as_float((w & 0xFFFFu) << 16);
  float t1 = __uint_as_float(w & 0xFFFF0000u);
  float o0 = (t0 * c - t1 * sn) * oscale;
  float o1 = (t0 * sn + t1 * c) * oscale;
  short* orow = outp + ((size_t)h * S_LEN + s) * HD;
  uint32_t pk = (uint32_t)(uint16_t)f2bf(o0) | ((uint32_t)(uint16_t)f2bf(o1) << 16);
  *(uint32_t*)&orow[2 * i] = pk;
}

// ---------------- bf16 GEMM: C[M][N] = A[M][K] * Bt[N][K]^T ----------------
// BM=128, BN=64, BK=32. 128 threads (2 waves stacked in M), acc 4x4 per wave.
template <bool BF16OUT>
__global__ __launch_bounds__(128) void gemm_bt(const short* __restrict__ A,
                                               const short* __restrict__ Bt,
                                               void* __restrict__ Cv,
                                               int M, int N, int K) {
  __shared__ char smem[12288];            // A tile 8KB [0,8192), B tile 4KB
  const int tid = threadIdx.x;
  const int wid = tid >> 6, lane = tid & 63;
  const int lq = lane & 15, g = lane >> 4;
  const int bm = blockIdx.y * 128, bn = blockIdx.x * 64;

  f32x4 acc[4][4] = {};

  const short* Asrc[4];
  const short* Bsrc[2];
#pragma unroll
  for (int u = 0; u < 4; u++) {
    int p = wid * 64 + u * 128 + lane;
    Asrc[u] = A + (size_t)(bm + (p >> 2)) * K + (p & 3) * 8;
  }
#pragma unroll
  for (int u = 0; u < 2; u++) {
    int p = wid * 64 + u * 128 + lane;
    Bsrc[u] = Bt + (size_t)(bn + (p >> 2)) * K + (p & 3) * 8;
  }
  char* la = smem;
  char* lb = smem + 8192;

  for (int k0 = 0; k0 < K; k0 += 32) {
    __syncthreads();
#pragma unroll
    for (int u = 0; u < 4; u++)
      gload16(Asrc[u] + k0, la + wid * 1024 + u * 2048);
#pragma unroll
    for (int u = 0; u < 2; u++)
      gload16(Bsrc[u] + k0, lb + wid * 1024 + u * 2048);
    __syncthreads();
    bf16x8_t af[4], bfr[4];
#pragma unroll
    for (int mi = 0; mi < 4; mi++)
      af[mi] = *(const bf16x8_t*)(la + (wid * 64 + mi * 16 + lq) * 64 + g * 16);
#pragma unroll
    for (int ni = 0; ni < 4; ni++)
      bfr[ni] = *(const bf16x8_t*)(lb + (ni * 16 + lq) * 64 + g * 16);
#pragma unroll
    for (int mi = 0; mi < 4; mi++)
#pragma unroll
      for (int ni = 0; ni < 4; ni++)
        acc[mi][ni] = __builtin_amdgcn_mfma_f32_16x16x32_bf16(af[mi], bfr[ni], acc[mi][ni], 0, 0, 0);
  }
#pragma unroll
  for (int mi = 0; mi < 4; mi++) {
#pragma unroll
    for (int r = 0; r < 4; r++) {
      int row = bm + wid * 64 + mi * 16 + g * 4 + r;
      if (BF16OUT) {
        short* Crow = (short*)Cv + (size_t)row * N + bn;
#pragma unroll
        for (int ni = 0; ni < 4; ni++)
          Crow[ni * 16 + lq] = f2bf(acc[mi][ni][r]);
      } else {
        float* Crow = (float*)Cv + (size_t)row * N + bn;
#pragma unroll
        for (int ni = 0; ni < 4; ni++)
          Crow[ni * 16 + lq] = acc[mi][ni][r];
      }
    }
  }
}

// ---------------- flash attention ----------------
// Q [NH][S][HD] bf16 (pre-scaled by 1/sqrt(HD)*log2e), K [NKV][S][HD], Vt [NKV][HD][S]
// -> Oatt [S][NH*HD] bf16.  256-thread blocks = 4 waves x 16 q-rows (QBLK=64).
// KVBLK=64, single-buffered 32KB LDS (m97 2-barrier structure; TLP covers drain).
// XOR-swizzle granule^(row&7) on both stage-source and read.  Grid: 512 blocks,
// big q-tiles first (qi = 31-bx).  Defer-max (T13) + setprio (T5).
__global__ __launch_bounds__(256, 3) void flash_attn(const short* __restrict__ Q,
                                                     const short* __restrict__ Kb,
                                                     const short* __restrict__ Vt,
                                                     short* __restrict__ Oatt) {
  __shared__ char smem[32768];   // K 16KB [0,16384), V 16KB [16384,32768)
  const int h = blockIdx.y, kvh = h >> 2;
  const int qi = 31 - blockIdx.x;          // big tiles dispatched first
  const int tid = threadIdx.x;
  const int wid = tid >> 6, lane = tid & 63;
  const int lq = lane & 15, g = lane >> 4;
  const short* Kh = Kb + (size_t)kvh * S_LEN * HD;
  const short* Vh = Vt + (size_t)kvh * HD * S_LEN;

  // staging source offsets (lane-dependent, tile-relative), swizzled granule
  int kOff[4], vOff[4];
#pragma unroll
  for (int u = 0; u < 4; u++) {
    int p = u * 256 + tid;
    int kr = p >> 4, kc = (p & 15) ^ (kr & 7);
    kOff[u] = kr * HD + kc * 8;          // shorts
    int vd = p >> 3, vc = (p & 7) ^ (vd & 7);
    vOff[u] = vd * S_LEN + vc * 8;       // shorts
  }
  const int swz = lq & 7;                // (row & 7) for all fragment reads

  const int q0 = qi * 64 + wid * 16;     // this wave's 16 rows
  const int nt_ = qi + 1;
  const int q_abs = q0 + lq;

  const short* Qb = Q + ((size_t)h * S_LEN + q0) * HD;
  bf16x8_t qf[4];
#pragma unroll
  for (int kk = 0; kk < 4; kk++)
    qf[kk] = *(const bf16x8_t*)(Qb + lq * HD + kk * 32 + g * 8);

  f32x4 oa[8] = {};
  float m_run = -1e30f, l_run = 0.f;

  for (int t = 0; t < nt_; ++t) {
    const int kv0 = t * 64;
    // --- stage K/V tile (single buffer; all waves past previous compute) ---
    const short* Ks = Kh + (size_t)kv0 * HD;
    const short* Vs = Vh + kv0;
#pragma unroll
    for (int u = 0; u < 4; u++) {
      gload16(Ks + kOff[u], smem + u * 4096 + wid * 1024);
      gload16(Vs + vOff[u], smem + 16384 + u * 4096 + wid * 1024);
    }
    __syncthreads();                     // drains vmcnt(0) -> tile ready

    // --- swapped QK^T: sc[sub][r] = score(q=q0+lq, kv=kv0+sub*16+4g+r) ---
    f32x4 sc[4] = {};
    __builtin_amdgcn_s_setprio(1);
#pragma unroll
    for (int sub = 0; sub < 4; sub++) {
      const char* krow = smem + (sub * 16 + lq) * 256;
#pragma unroll
      for (int kk = 0; kk < 4; kk++) {
        bf16x8_t kf = *(const bf16x8_t*)(krow + (((kk * 4 + g) ^ swz) << 4));
        sc[sub] = __builtin_amdgcn_mfma_f32_16x16x32_bf16(kf, qf[kk], sc[sub], 0, 0, 0);
      }
    }
    __builtin_amdgcn_s_setprio(0);

    // --- online softmax (log2 domain; Q pre-scaled), mask only on diagonal tile ---
    float s16[16];
    if (t == nt_ - 1) {
#pragma unroll
      for (int sub = 0; sub < 4; sub++)
#pragma unroll
        for (int r = 0; r < 4; r++) {
          int kva = kv0 + sub * 16 + 4 * g + r;
          s16[sub * 4 + r] = (kva <= q_abs) ? sc[sub][r] : -1e30f;
        }
    } else {
#pragma unroll
      for (int sub = 0; sub < 4; sub++)
#pragma unroll
        for (int r = 0; r < 4; r++)
          s16[sub * 4 + r] = sc[sub][r];
    }
    float mx = s16[0];
#pragma unroll
    for (int j = 1; j < 16; j++) mx = fmaxf(mx, s16[j]);
    mx = fmaxf(mx, __shfl_xor(mx, 16));
    mx = fmaxf(mx, __shfl_xor(mx, 32));

    // defer-max: skip rescale while tile max stays within 2^11 of running max
    if (!__all(mx <= m_run + 11.0f)) {
      float m_new = fmaxf(m_run, mx);
      float fl = exp2f(m_run - m_new);
      float fr[4];
#pragma unroll
      for (int r = 0; r < 4; r++) fr[r] = __shfl(fl, 4 * g + r);
#pragma unroll
      for (int nt = 0; nt < 8; nt++)
#pragma unroll
        for (int r = 0; r < 4; r++) oa[nt][r] *= fr[r];
      l_run *= fl;
      m_run = m_new;
    }
    float p16[16], psum = 0.f;
#pragma unroll
    for (int j = 0; j < 16; j++) { p16[j] = exp2f(s16[j] - m_run); psum += p16[j]; }
    psum += __shfl_xor(psum, 16);
    psum += __shfl_xor(psum, 32);
    l_run += psum;

    bf16x8_t pf0, pf1;
#pragma unroll
    for (int j = 0; j < 8; j++) { pf0[j] = f2bf(p16[j]); pf1[j] = f2bf(p16[8 + j]); }

    // --- PV: O += P * V ---
    const int gh = g >> 1;
    __builtin_amdgcn_s_setprio(1);
#pragma unroll
    for (int nt = 0; nt < 8; nt++) {
      const char* vrow = smem + 16384 + (nt * 16 + lq) * 128 + (g & 1) * 8;
#pragma unroll
      for (int ks = 0; ks < 2; ks++) {
        bf16x4_t v0 = *(const bf16x4_t*)(vrow + (((ks * 4 + gh) ^ swz) << 4));
        bf16x4_t v1 = *(const bf16x4_t*)(vrow + (((ks * 4 + 2 + gh) ^ swz) << 4));
        bf16x8_t vf;
#pragma unroll
        for (int j = 0; j < 4; j++) { vf[j] = v0[j]; vf[4 + j] = v1[j]; }
        oa[nt] = __builtin_amdgcn_mfma_f32_16x16x32_bf16(ks ? pf1 : pf0, vf, oa[nt], 0, 0, 0);
      }
    }
    __builtin_amdgcn_s_setprio(0);
    if (t + 1 < nt_) __syncthreads();    // all waves done reading before restage
  }

  // --- finalize: O /= l, write bf16 ---
  float lr[4];
#pragma unroll
  for (int r = 0; r < 4; r++) lr[r] = 1.0f / __shfl(l_run, 4 * g + r);
#pragma unroll
  for (int nt = 0; nt < 8; nt++)
#pragma unroll
    for (int r = 0; r < 4; r++) {
      int row = q0 + 4 * g + r;
      Oatt[(size_t)row * (NH * HD) + h * HD + nt * 16 + lq] = f2bf(oa[nt][r] * lr[r]);
    }
}

// ---------------- launch ----------------
extern "C" void kernel_launch(void* const* d_in, const int* in_sizes, int n_in,
                              void* d_out, int out_size, void* d_ws, size_t ws_size,
                              hipStream_t stream) {
  const float* x  = (const float*)d_in[0];
  const float* wq = (const float*)d_in[1];
  const float* wk = (const float*)d_in[2];
  const float* wv = (const float*)d_in[3];
  const float* wo = (const float*)d_in[4];
  const float* fc = (const float*)d_in[5];
  const float* fs = (const float*)d_in[6];
  // d_in[7] (mask) is exactly causal tril -> applied analytically
  float* out = (float*)d_out;

  char* ws = (char*)d_ws;
  const size_t MB = 1024 * 1024;
  if (ws_size < 64 * MB) return;
  short* xb    = (short*)(ws);            // 8MB  x bf16 [S][D]
  short* wqkvT = (short*)(ws + 8 * MB);   // 12MB [3072][2048] (wq^T | wk^T | wv^T)
  short* woT   = (short*)(ws + 20 * MB);  // 8MB  [2048][2048]
  short* xqkvb = (short*)(ws + 28 * MB);  // 12MB x@wqkv bf16 [2048][3072]
  short* qbf   = (short*)(ws + 40 * MB);  // 8MB  [NH][S][HD]
  short* kbf   = (short*)(ws + 48 * MB);  // 2MB  [NKV][S][HD]
  short* vT    = (short*)(ws + 50 * MB);  // 2MB  [NKV][HD][S]
  short* abf   = (short*)(ws + 52 * MB);  // 8MB  attn out bf16 [S][NH*HD]

  const float scale2 = 0.0883883476483184f * 1.4426950408889634f; // 1/sqrt(HD)*log2e

  dim3 tb(32, 8);
  cvt_bf16<<<2048, 256, 0, stream>>>(x, xb, (S_LEN * DMODEL) / 8);
  transpose_f32_bf16<<<dim3(64, 64, 1), tb, 0, stream>>>(wq, wqkvT, 2048, 2048, 0, 0);
  transpose_f32_bf16<<<dim3(16, 64, 1), tb, 0, stream>>>(wk, wqkvT + (size_t)2048 * 2048, 512, 2048, 0, 0);
  transpose_f32_bf16<<<dim3(16, 64, 1), tb, 0, stream>>>(wv, wqkvT + (size_t)2560 * 2048, 512, 2048, 0, 0);
  transpose_f32_bf16<<<dim3(64, 64, 1), tb, 0, stream>>>(wo, woT, 2048, 2048, 0, 0);

  // fused QKV projection: [2048][2048] x [2048][3072] -> xqkvb bf16 [2048][3072]
  gemm_bt<true><<<dim3(48, 16), 128, 0, stream>>>(xb, wqkvT, xqkvb, 2048, 3072, 2048);

  rope_heads<<<dim3(2048, 4), dim3(64, 4), 0, stream>>>(xqkvb, fc, fs, qbf, 3072, scale2);
  rope_heads<<<dim3(2048, 1), dim3(64, 4), 0, stream>>>(xqkvb + 2048, fc, fs, kbf, 3072, 1.0f);
  // V^T per kv head: cols [2560 + z*128, ...+128) of xqkvb -> vT[z][d][s]
  transpose_bf16<<<dim3(4, 64, 4), tb, 0, stream>>>(xqkvb + 2560, vT, 3072, 2048, 128, 128L * 2048);

  flash_attn<<<dim3(32, 16), 256, 0, stream>>>(qbf, kbf, vT, abf);

  // output projection
  gemm_bt<false><<<dim3(32, 16), 128, 0, stream>>>(abf, woT, out, 2048, 2048, 2048);
}